// Round 20
// baseline (72.463 us; speedup 1.0000x reference)
//
#include <hip/hip_runtime.h>
#include <math.h>

#define KCOMP 32
#define DDIM 64
#define LOG_2PI 1.8378770664093453f

// W~ fragment-major layout: frag index f = (comp*2 + r)*5 + s, each frag is
// 1024 B = 64 lanes x 16 B (one half8 per lane). Per comp: 10 frags = 10240 B.
#define WFRAG_HALF8S 64
#define WCOMP_BYTES 10240

typedef _Float16 half8 __attribute__((ext_vector_type(8)));
typedef float floatx16 __attribute__((ext_vector_type(16)));
typedef float float2v __attribute__((ext_vector_type(2)));

__device__ inline float rdlane(float v, int l) {
    return __uint_as_float(__builtin_amdgcn_readlane(__float_as_uint(v), l));
}

// ---------------------------------------------------------------------------
// DUAL-component fused Cholesky + triangular-inverse step (template J).
// Two INDEPENDENT components (A, B) interleaved in one wave: every
// rdlane->fma / rsqrt / chain stall of one component is filled by the
// sibling's independent work (per-comp fetch bytes unchanged: 2x code / 2
// comps). Packed pairs LM[c] = (L[t][c], M[c][t]) as in R16/R18 (best
// measured structure). Sigma rows stream from global with one-step
// prefetch-carry (L1-resident; frees 128 VGPRs vs resident Srow).
// Tail batch of 4 when J%8 <= 4 (padding exact: LM zero-init).
// ---------------------------------------------------------------------------
template <int J>
__device__ __forceinline__ void fused_step2(const float* __restrict__ sgA,
                                            const float* __restrict__ sgB,
                                            float2v (&LA)[DDIM], float2v (&LB)[DDIM],
                                            float& diagA, float& diagB,
                                            float& sA, float& sB, const int t) {
    // issue next-step Sigma loads first (consumed at step J+1; L1-hot lines)
    float snA = 0.f, snB = 0.f;
    if constexpr (J + 1 < DDIM) {
        snA = sgA[J + 1];
        snB = sgB[J + 1];
    }

    constexpr int NB8  = J / 8;
    constexpr int REM  = J - NB8 * 8;
    constexpr int TAIL = (REM == 0) ? 0 : (REM <= 4 ? 4 : 8);

    float2v aA0 = {0.f,0.f}, aA1 = {0.f,0.f}, aA2 = {0.f,0.f}, aA3 = {0.f,0.f};
    float2v aB0 = {0.f,0.f}, aB1 = {0.f,0.f}, aB2 = {0.f,0.f}, aB3 = {0.f,0.f};

    #pragma unroll
    for (int p8 = 0; p8 < NB8 * 8; p8 += 8) {
        float bA[8], bB[8];
        #pragma unroll
        for (int e = 0; e < 8; ++e) bA[e] = rdlane(LA[p8 + e].x, J);
        #pragma unroll
        for (int e = 0; e < 8; ++e) bB[e] = rdlane(LB[p8 + e].x, J);
        #pragma unroll
        for (int e = 0; e < 8; ++e) {
            float2v bbA = {bA[e], bA[e]};
            float2v bbB = {bB[e], bB[e]};
            switch (e & 3) {
                case 0: aA0 += LA[p8 + e] * bbA; aB0 += LB[p8 + e] * bbB; break;
                case 1: aA1 += LA[p8 + e] * bbA; aB1 += LB[p8 + e] * bbB; break;
                case 2: aA2 += LA[p8 + e] * bbA; aB2 += LB[p8 + e] * bbB; break;
                default: aA3 += LA[p8 + e] * bbA; aB3 += LB[p8 + e] * bbB; break;
            }
        }
    }
    if constexpr (TAIL > 0) {
        constexpr int base = NB8 * 8;
        float bA[8], bB[8];
        #pragma unroll
        for (int e = 0; e < TAIL; ++e) bA[e] = rdlane(LA[base + e].x, J);
        #pragma unroll
        for (int e = 0; e < TAIL; ++e) bB[e] = rdlane(LB[base + e].x, J);
        #pragma unroll
        for (int e = 0; e < TAIL; ++e) {
            float2v bbA = {bA[e], bA[e]};
            float2v bbB = {bB[e], bB[e]};
            switch (e & 3) {
                case 0: aA0 += LA[base + e] * bbA; aB0 += LB[base + e] * bbB; break;
                case 1: aA1 += LA[base + e] * bbA; aB1 += LB[base + e] * bbB; break;
                case 2: aA2 += LA[base + e] * bbA; aB2 += LB[base + e] * bbB; break;
                default: aA3 += LA[base + e] * bbA; aB3 += LB[base + e] * bbB; break;
            }
        }
    }

    float2v redA = (aA0 + aA1) + (aA2 + aA3);
    float2v redB = (aB0 + aB1) + (aB2 + aB3);

    float vA = sA - redA.x;
    float vB = sB - redB.x;
    float djA = rdlane(vA, J);               // uniform diagonals
    float djB = rdlane(vB, J);
    float rA = rsqrtf(djA);                  // v_rsq_f32 (~1 ulp) sufficient
    float rB = rsqrtf(djB);
    float lvA = (t >= J) ? vA * rA : 0.f;
    float lvB = (t >= J) ? vB * rB : 0.f;
    float mvA = (t < J) ? (-redA.y * rA) : ((t == J) ? rA : 0.f);
    float mvB = (t < J) ? (-redB.y * rB) : ((t == J) ? rB : 0.f);
    LA[J] = (float2v){lvA, mvA};
    LB[J] = (float2v){lvB, mvB};
    if (t == J) { diagA = djA; diagB = djB; }
    sA = snA;
    sB = snB;
}

template <int J>
__device__ __forceinline__ void fused_run2(const float* __restrict__ sgA,
                                           const float* __restrict__ sgB,
                                           float2v (&LA)[DDIM], float2v (&LB)[DDIM],
                                           float& diagA, float& diagB,
                                           float& sA, float& sB, const int t) {
    fused_step2<J>(sgA, sgB, LA, LB, diagA, diagB, sA, sB, t);
    if constexpr (J + 1 < DDIM)
        fused_run2<J + 1>(sgA, sgB, LA, LB, diagA, diagB, sA, sB, t);
}

// ---------------------------------------------------------------------------
// Emit one component: flush M to LDS, compute b, write fragment-major f16 W~,
// logdet wave-sum + cst. Called twice (comp A, then B) reusing the buffers.
// ---------------------------------------------------------------------------
__device__ __forceinline__ void emit_comp(const int k, const int t,
                                          const float2v (&LM)[DDIM], float mydiag,
                                          const float* __restrict__ loc,
                                          const float* __restrict__ pi,
                                          _Float16* __restrict__ wt,
                                          float* __restrict__ cstout,
                                          float (*M)[DDIM + 1],
                                          float* __restrict__ mu_s) {
    // flush M columns -> LDS rows (in-wave DS ordering; single wave)
    #pragma unroll
    for (int i = 0; i < DDIM; ++i) M[i][t] = LM[i].y;
    mu_s[t] = loc[k * DDIM + t];
    __syncthreads();   // single-wave: cheap s_barrier, guards cross-lane reads

    float bt = 0.f;
    #pragma unroll 4
    for (int j = 0; j < DDIM; ++j) bt += M[t][j] * mu_s[j];

    {
        const int r = t >> 5, lrow = t & 31;
        half8* wp = (half8*)wt;
        const size_t fbase = ((size_t)k * 2 + r) * 5;
        #pragma unroll
        for (int c = 0; c < 8; ++c) {
            half8 v;
            #pragma unroll
            for (int e = 0; e < 8; ++e) v[e] = (_Float16)M[t][c * 8 + e];
            int fl = lrow + 32 * (c & 1);
            wp[(fbase + (c >> 1)) * WFRAG_HALF8S + fl] = v;
        }
        {   // chunk 8: -b split hi/lo (pairs with x~=1,1)
            float nb = -bt;
            _Float16 h0 = (_Float16)nb;
            _Float16 h1 = (_Float16)(nb - (float)h0);
            half8 v;
            #pragma unroll
            for (int e = 0; e < 8; ++e) v[e] = (_Float16)0.f;
            v[0] = h0; v[1] = h1;
            wp[(fbase + 4) * WFRAG_HALF8S + lrow] = v;
        }
        {   // chunk 9: zeros
            half8 v;
            #pragma unroll
            for (int e = 0; e < 8; ++e) v[e] = (_Float16)0.f;
            wp[(fbase + 4) * WFRAG_HALF8S + lrow + 32] = v;
        }
    }

    float hld;
    {
        float lg = 0.5f * logf(mydiag);
        #pragma unroll
        for (int w = 1; w < 64; w <<= 1) lg += __shfl_xor(lg, w);
        hld = lg;
    }
    if (t == 0) {
        float mxp = pi[0];
        for (int i = 1; i < KCOMP; ++i) mxp = fmaxf(mxp, pi[i]);
        float s = 0.f;
        for (int i = 0; i < KCOMP; ++i) s += __expf(pi[i] - mxp);
        float lse = mxp + logf(s);
        cstout[k] = (pi[k] - lse) - hld - 0.5f * (float)DDIM * LOG_2PI;
    }
    __syncthreads();   // buffer reuse guard before next emit
}

// ---------------------------------------------------------------------------
// Prep: TWO components per wave (interleaved chains), one wave per block.
// grid = KCOMP/2 blocks x 64 threads.
// ---------------------------------------------------------------------------
__global__ __launch_bounds__(64, 1) void gmm_prep(const float* __restrict__ loc,
                                                  const float* __restrict__ cov,
                                                  const float* __restrict__ pi,
                                                  _Float16* __restrict__ wt,
                                                  float* __restrict__ cstout)
{
    const int kA = blockIdx.x * 2;
    const int kB = kA + 1;
    const int t  = threadIdx.x;

    __shared__ float M[DDIM][DDIM + 1];
    __shared__ float mu_s[DDIM];

    float2v LA[DDIM];   // (L[t][c], M[c][t]) comp A (zero-init: padding exact)
    float2v LB[DDIM];   // comp B

    #pragma unroll
    for (int i = 0; i < DDIM; ++i) {
        LA[i] = (float2v){0.f, 0.f};
        LB[i] = (float2v){0.f, 0.f};
    }

    const float* sgA = cov + (size_t)kA * DDIM * DDIM + (size_t)t * DDIM;
    const float* sgB = cov + (size_t)kB * DDIM * DDIM + (size_t)t * DDIM;

    float diagA = 1.f, diagB = 1.f;
    float sA = sgA[0], sB = sgB[0];

    fused_run2<0>(sgA, sgB, LA, LB, diagA, diagB, sA, sB, t);

    emit_comp(kA, t, LA, diagA, loc, pi, wt, cstout, M, mu_s);
    emit_comp(kB, t, LB, diagB, loc, pi, wt, cstout, M, mu_s);
}

// ---------------------------------------------------------------------------
// Main: UNCHANGED from round 8 (near MFMA/L2 floor). No LDS staging, no
// hot-loop barriers. Block = 4 waves = 4 component slices (8 comps each)
// over the SAME 128 points; W~ streams L2 -> regs double-buffered.
// ---------------------------------------------------------------------------
__global__ __launch_bounds__(256, 1) void gmm_main(const float* __restrict__ X,
                                                   const _Float16* __restrict__ wt,
                                                   const float* __restrict__ cst,
                                                   float* __restrict__ out)
{
    __shared__ float2 part[4][128];       // [slice][point] partial (mx, sm)

    const int tid  = threadIdx.x;
    const int wave = tid >> 6;            // = component slice
    const int lane = tid & 63;
    const int col  = lane & 31;
    const int h    = lane >> 5;
    const int ptbase = blockIdx.x * 128;

    // ---- build B fragments (x~) for 4 point-groups of 32 ----
    half8 bf[4][5];
    #pragma unroll
    for (int g = 0; g < 4; ++g) {
        const float* xr = X + (size_t)(ptbase + g * 32 + col) * DDIM;
        #pragma unroll
        for (int s = 0; s < 4; ++s) {
            int c = s * 2 + h;
            float4 lo = *(const float4*)(xr + c * 8);
            float4 hi = *(const float4*)(xr + c * 8 + 4);
            half8 v;
            v[0] = (_Float16)lo.x; v[1] = (_Float16)lo.y;
            v[2] = (_Float16)lo.z; v[3] = (_Float16)lo.w;
            v[4] = (_Float16)hi.x; v[5] = (_Float16)hi.y;
            v[6] = (_Float16)hi.z; v[7] = (_Float16)hi.w;
            bf[g][s] = v;
        }
        half8 v;
        #pragma unroll
        for (int e = 0; e < 8; ++e) v[e] = (_Float16)0.f;
        if (h == 0) { v[0] = (_Float16)1.f; v[1] = (_Float16)1.f; }
        bf[g][4] = v;   // augmented slice: pairs with (-b_hi, -b_lo)
    }

    const half8* wp = (const half8*)wt;
    const int comp0 = wave * 8;

    float mx[4], sm[4];
    #pragma unroll
    for (int g = 0; g < 4; ++g) { mx[g] = -INFINITY; sm[g] = 0.f; }

    half8 wfA[5], wfB[5];
    // preload tile-0 frags of first comp
    #pragma unroll
    for (int s = 0; s < 5; ++s)
        wfA[s] = wp[((size_t)comp0 * 2 + 0) * 5 * WFRAG_HALF8S + s * WFRAG_HALF8S + lane];

    #pragma unroll 1
    for (int q = 0; q < 8; ++q) {
        const int c = comp0 + q;

        // issue tile-1 frag loads (overlap with tile-0 MFMA below)
        #pragma unroll
        for (int s = 0; s < 5; ++s)
            wfB[s] = wp[((size_t)c * 2 + 1) * 5 * WFRAG_HALF8S + s * WFRAG_HALF8S + lane];

        float sP[4];

        {   // tile 0: z-rows 0..31
            floatx16 a0 = {0.f}, a1 = {0.f}, a2 = {0.f}, a3 = {0.f};
            #pragma unroll
            for (int s = 0; s < 5; ++s) {
                a0 = __builtin_amdgcn_mfma_f32_32x32x16_f16(wfA[s], bf[0][s], a0, 0, 0, 0);
                a1 = __builtin_amdgcn_mfma_f32_32x32x16_f16(wfA[s], bf[1][s], a1, 0, 0, 0);
                a2 = __builtin_amdgcn_mfma_f32_32x32x16_f16(wfA[s], bf[2][s], a2, 0, 0, 0);
                a3 = __builtin_amdgcn_mfma_f32_32x32x16_f16(wfA[s], bf[3][s], a3, 0, 0, 0);
            }
            float p0 = 0.f, p1 = 0.f, p2 = 0.f, p3 = 0.f;
            #pragma unroll
            for (int r = 0; r < 16; ++r) {
                p0 += a0[r] * a0[r]; p1 += a1[r] * a1[r];
                p2 += a2[r] * a2[r]; p3 += a3[r] * a3[r];
            }
            sP[0] = p0; sP[1] = p1; sP[2] = p2; sP[3] = p3;
        }

        // issue next comp's tile-0 loads (overlap with tile-1 MFMA below)
        if (q < 7) {
            #pragma unroll
            for (int s = 0; s < 5; ++s)
                wfA[s] = wp[((size_t)(c + 1) * 2 + 0) * 5 * WFRAG_HALF8S + s * WFRAG_HALF8S + lane];
        }

        {   // tile 1: z-rows 32..63
            floatx16 a0 = {0.f}, a1 = {0.f}, a2 = {0.f}, a3 = {0.f};
            #pragma unroll
            for (int s = 0; s < 5; ++s) {
                a0 = __builtin_amdgcn_mfma_f32_32x32x16_f16(wfB[s], bf[0][s], a0, 0, 0, 0);
                a1 = __builtin_amdgcn_mfma_f32_32x32x16_f16(wfB[s], bf[1][s], a1, 0, 0, 0);
                a2 = __builtin_amdgcn_mfma_f32_32x32x16_f16(wfB[s], bf[2][s], a2, 0, 0, 0);
                a3 = __builtin_amdgcn_mfma_f32_32x32x16_f16(wfB[s], bf[3][s], a3, 0, 0, 0);
            }
            float p0 = 0.f, p1 = 0.f, p2 = 0.f, p3 = 0.f;
            #pragma unroll
            for (int r = 0; r < 16; ++r) {
                p0 += a0[r] * a0[r]; p1 += a1[r] * a1[r];
                p2 += a2[r] * a2[r]; p3 += a3[r] * a3[r];
            }
            sP[0] += p0; sP[1] += p1; sP[2] += p2; sP[3] += p3;
        }

        const float ck = cst[c];
        #pragma unroll
        for (int g = 0; g < 4; ++g) {
            float sfull = sP[g] + __shfl_xor(sP[g], 32);
            float lp = ck - 0.5f * sfull;
            float nm = fmaxf(mx[g], lp);
            sm[g] = sm[g] * __expf(mx[g] - nm) + __expf(lp - nm);
            mx[g] = nm;
        }
    }

    // ---- merge the 4 slices in-block ----
    if (h == 0) {
        #pragma unroll
        for (int g = 0; g < 4; ++g)
            part[wave][g * 32 + col] = make_float2(mx[g], sm[g]);
    }
    __syncthreads();

    if (tid < 128) {
        float2 p0 = part[0][tid], p1 = part[1][tid];
        float2 p2 = part[2][tid], p3 = part[3][tid];
        float m = fmaxf(fmaxf(p0.x, p1.x), fmaxf(p2.x, p3.x));
        float s = p0.y * __expf(p0.x - m) + p1.y * __expf(p1.x - m)
                + p2.y * __expf(p2.x - m) + p3.y * __expf(p3.x - m);
        out[ptbase + tid] = m + logf(s);
    }
}

// ---------------------------------------------------------------------------
extern "C" void kernel_launch(void* const* d_in, const int* in_sizes, int n_in,
                              void* d_out, int out_size, void* d_ws, size_t ws_size,
                              hipStream_t stream) {
    const float* X   = (const float*)d_in[0];
    const float* loc = (const float*)d_in[1];
    const float* cov = (const float*)d_in[2];
    const float* pi  = (const float*)d_in[3];
    float* out = (float*)d_out;

    char* ws = (char*)d_ws;
    _Float16* wt = (_Float16*)ws;                              // 320 KB
    float* cstp  = (float*)(ws + (size_t)KCOMP * WCOMP_BYTES); // 128 B

    const int n = in_sizes[0] / DDIM;   // 65536

    gmm_prep<<<KCOMP / 2, 64, 0, stream>>>(loc, cov, pi, wt, cstp);
    gmm_main<<<n / 128, 256, 0, stream>>>(X, wt, cstp, out);
}

// Round 21
// 45.905 us; speedup vs baseline: 1.5785x; 1.5785x over previous
//
#include <hip/hip_runtime.h>
#include <math.h>

#define KCOMP 32
#define DDIM 64
#define LOG_2PI 1.8378770664093453f

// W~ fragment-major layout: frag index f = (comp*2 + r)*5 + s, each frag is
// 1024 B = 64 lanes x 16 B (one half8 per lane). Per comp: 10 frags = 10240 B.
#define WFRAG_HALF8S 64
#define WCOMP_BYTES 10240

typedef _Float16 half8 __attribute__((ext_vector_type(8)));
typedef float floatx16 __attribute__((ext_vector_type(16)));
typedef float float2v __attribute__((ext_vector_type(2)));

__device__ inline float rdlane(float v, int l) {
    return __uint_as_float(__builtin_amdgcn_readlane(__float_as_uint(v), l));
}

// ---------------------------------------------------------------------------
// FUSED Cholesky + triangular-inverse step, fully static (template J),
// with PACKED fp32 pairs: LM[c] = (L[t][c], M[c][t]) lives in an even-
// aligned VGPR pair, so the fused dot is ONE v_pk_fma_f32 per term:
//   am[e].x += LM[c].x * b   (chol dot:  L[t][c] * L[J][c])
//   am[e].y += LM[c].y * b   (inv  dot:  M[c][t] * L[J][c])
// [R16 structure — measured optimum across 12 prep variants: unrolled body,
// register operands, readlane broadcasts, 1 wave/block. Packed waves (R12/
// R14/R19/R20), LDS operands (R13/R15/R17), and further inst cuts (R18)
// all measured null or worse.]
// Padding safety: LM zero-init; at step J, LM[c>=J] = 0.
// ---------------------------------------------------------------------------
template <int J>
__device__ __forceinline__ void fused_step(float (&Srow)[DDIM], float2v (&LM)[DDIM],
                                           float& mydiag, const int t) {
    constexpr int NPAD = ((J + 7) / 8) * 8;
    float2v am[8];
    #pragma unroll
    for (int e = 0; e < 8; ++e) am[e] = (float2v){0.f, 0.f};
    #pragma unroll
    for (int p8 = 0; p8 < NPAD; p8 += 8) {
        float b[8];
        #pragma unroll
        for (int e = 0; e < 8; ++e) b[e] = rdlane(LM[p8 + e].x, J);  // L[J][c]
        #pragma unroll
        for (int e = 0; e < 8; ++e) {
            float2v bb = {b[e], b[e]};
            am[e] += LM[p8 + e] * bb;        // v_pk_fma_f32
        }
    }
    float2v red = ((am[0] + am[1]) + (am[2] + am[3]))
                + ((am[4] + am[5]) + (am[6] + am[7]));
    float dot = red.x;
    float ms  = red.y;
    float v  = Srow[J] - dot;
    float dj = rdlane(v, J);                 // diagonal d_J (pre-sqrt), uniform
    float r  = rsqrtf(dj);
    r = r * (1.5f - 0.5f * dj * r * r);      // one Newton step
    float lv = (t >= J) ? v * r : 0.f;
    float mv = (t < J) ? (-ms * r) : ((t == J) ? r : 0.f);
    LM[J] = (float2v){lv, mv};
    if (t == J) mydiag = dj;
}

template <int J>
__device__ __forceinline__ void fused_run(float (&Srow)[DDIM], float2v (&LM)[DDIM],
                                          float& mydiag, const int t) {
    fused_step<J>(Srow, LM, mydiag, t);
    if constexpr (J + 1 < DDIM) fused_run<J + 1>(Srow, LM, mydiag, t);
}

// ---------------------------------------------------------------------------
// Prep: register-resident fused Cholesky+inverse, one wave/component.
// Launch shape: 32 blocks x 64 thr (best measured, R11/R12/R14 A/B series).
// ---------------------------------------------------------------------------
__global__ __launch_bounds__(64, 1) void gmm_prep(const float* __restrict__ loc,
                                                  const float* __restrict__ cov,
                                                  const float* __restrict__ pi,
                                                  _Float16* __restrict__ wt,
                                                  float* __restrict__ cstout)
{
    const int k = blockIdx.x;
    const int t = threadIdx.x;

    __shared__ float M[DDIM][DDIM + 1];
    __shared__ float mu_s[DDIM];

    float Srow[DDIM];     // Sigma row t
    float2v LM[DDIM];     // (L[t][c], M[c][t]) pairs (zero-init: padding safety)

    {
        const float4* Sg = (const float4*)(cov + (size_t)k * DDIM * DDIM + (size_t)t * DDIM);
        #pragma unroll
        for (int q = 0; q < DDIM / 4; ++q) {
            float4 v = Sg[q];
            Srow[q * 4 + 0] = v.x; Srow[q * 4 + 1] = v.y;
            Srow[q * 4 + 2] = v.z; Srow[q * 4 + 3] = v.w;
        }
    }
    #pragma unroll
    for (int i = 0; i < DDIM; ++i) LM[i] = (float2v){0.f, 0.f};
    mu_s[t] = loc[k * DDIM + t];

    // ---- fused left-looking Cholesky + forward-substitution inverse ----
    float mydiag = 1.f;                      // lane t ends holding d_t
    fused_run<0>(Srow, LM, mydiag, t);

    // half-logdet = sum_j 0.5*log(d_j): one logf per lane + wave-sum
    float hld;
    {
        float lg = 0.5f * logf(mydiag);
        #pragma unroll
        for (int w = 1; w < 64; w <<= 1) lg += __shfl_xor(lg, w);
        hld = lg;
    }

    // flush M columns -> LDS rows (one time)
    #pragma unroll
    for (int i = 0; i < DDIM; ++i) M[i][t] = LM[i].y;
    __syncthreads();

    // ---- b_t = sum_j M[t][j] * mu[j] (upper of M is zero) ----
    float bt = 0.f;
    #pragma unroll 4
    for (int j = 0; j < DDIM; ++j) bt += M[t][j] * mu_s[j];

    // ---- emit fragment-major f16 W~: thread t = z-row t ----
    // A-frag for mfma_32x32x16_f16: lane l holds A[l&31][(l>>5)*8 + e].
    // Row t, feature chunk c (8 halves) -> frag s = c>>1, frag-lane
    // fl = (t&31) + 32*(c&1), tile r = t>>5.
    {
        const int r = t >> 5, lrow = t & 31;
        half8* wp = (half8*)wt;
        const size_t fbase = ((size_t)k * 2 + r) * 5;   // frag index base
        #pragma unroll
        for (int c = 0; c < 8; ++c) {          // data chunks: M row
            half8 v;
            #pragma unroll
            for (int e = 0; e < 8; ++e) v[e] = (_Float16)M[t][c * 8 + e];
            int fl = lrow + 32 * (c & 1);
            wp[(fbase + (c >> 1)) * WFRAG_HALF8S + fl] = v;
        }
        {   // chunk 8 (s=4, fl=lrow): -b split hi/lo (pairs with x~=1,1)
            float nb = -bt;
            _Float16 h0 = (_Float16)nb;
            _Float16 h1 = (_Float16)(nb - (float)h0);
            half8 v;
            #pragma unroll
            for (int e = 0; e < 8; ++e) v[e] = (_Float16)0.f;
            v[0] = h0; v[1] = h1;
            wp[(fbase + 4) * WFRAG_HALF8S + lrow] = v;
        }
        {   // chunk 9 (s=4, fl=lrow+32): zeros
            half8 v;
            #pragma unroll
            for (int e = 0; e < 8; ++e) v[e] = (_Float16)0.f;
            wp[(fbase + 4) * WFRAG_HALF8S + lrow + 32] = v;
        }
    }

    if (t == 0) {
        float mxp = pi[0];
        for (int i = 1; i < KCOMP; ++i) mxp = fmaxf(mxp, pi[i]);
        float s = 0.f;
        for (int i = 0; i < KCOMP; ++i) s += __expf(pi[i] - mxp);
        float lse = mxp + logf(s);
        cstout[k] = (pi[k] - lse) - hld - 0.5f * (float)DDIM * LOG_2PI;
    }
}

// ---------------------------------------------------------------------------
// Main: UNCHANGED from round 8 (near MFMA/L2 floor: ~11 us vs ~8.5 us MFMA
// issue floor). No LDS staging, no hot-loop barriers. Block = 4 waves = 4
// component slices (8 comps each) over the SAME 128 points; W~ fragments
// stream L2 -> regs (coalesced 1 KB loads), double-buffered wfA/wfB.
// ---------------------------------------------------------------------------
__global__ __launch_bounds__(256, 1) void gmm_main(const float* __restrict__ X,
                                                   const _Float16* __restrict__ wt,
                                                   const float* __restrict__ cst,
                                                   float* __restrict__ out)
{
    __shared__ float2 part[4][128];       // [slice][point] partial (mx, sm)

    const int tid  = threadIdx.x;
    const int wave = tid >> 6;            // = component slice
    const int lane = tid & 63;
    const int col  = lane & 31;
    const int h    = lane >> 5;
    const int ptbase = blockIdx.x * 128;

    // ---- build B fragments (x~) for 4 point-groups of 32 ----
    half8 bf[4][5];
    #pragma unroll
    for (int g = 0; g < 4; ++g) {
        const float* xr = X + (size_t)(ptbase + g * 32 + col) * DDIM;
        #pragma unroll
        for (int s = 0; s < 4; ++s) {
            int c = s * 2 + h;
            float4 lo = *(const float4*)(xr + c * 8);
            float4 hi = *(const float4*)(xr + c * 8 + 4);
            half8 v;
            v[0] = (_Float16)lo.x; v[1] = (_Float16)lo.y;
            v[2] = (_Float16)lo.z; v[3] = (_Float16)lo.w;
            v[4] = (_Float16)hi.x; v[5] = (_Float16)hi.y;
            v[6] = (_Float16)hi.z; v[7] = (_Float16)hi.w;
            bf[g][s] = v;
        }
        half8 v;
        #pragma unroll
        for (int e = 0; e < 8; ++e) v[e] = (_Float16)0.f;
        if (h == 0) { v[0] = (_Float16)1.f; v[1] = (_Float16)1.f; }
        bf[g][4] = v;   // augmented slice: pairs with (-b_hi, -b_lo)
    }

    const half8* wp = (const half8*)wt;
    const int comp0 = wave * 8;

    float mx[4], sm[4];
    #pragma unroll
    for (int g = 0; g < 4; ++g) { mx[g] = -INFINITY; sm[g] = 0.f; }

    half8 wfA[5], wfB[5];
    // preload tile-0 frags of first comp
    #pragma unroll
    for (int s = 0; s < 5; ++s)
        wfA[s] = wp[((size_t)comp0 * 2 + 0) * 5 * WFRAG_HALF8S + s * WFRAG_HALF8S + lane];

    #pragma unroll 1
    for (int q = 0; q < 8; ++q) {
        const int c = comp0 + q;

        // issue tile-1 frag loads (overlap with tile-0 MFMA below)
        #pragma unroll
        for (int s = 0; s < 5; ++s)
            wfB[s] = wp[((size_t)c * 2 + 1) * 5 * WFRAG_HALF8S + s * WFRAG_HALF8S + lane];

        float sP[4];

        {   // tile 0: z-rows 0..31
            floatx16 a0 = {0.f}, a1 = {0.f}, a2 = {0.f}, a3 = {0.f};
            #pragma unroll
            for (int s = 0; s < 5; ++s) {
                a0 = __builtin_amdgcn_mfma_f32_32x32x16_f16(wfA[s], bf[0][s], a0, 0, 0, 0);
                a1 = __builtin_amdgcn_mfma_f32_32x32x16_f16(wfA[s], bf[1][s], a1, 0, 0, 0);
                a2 = __builtin_amdgcn_mfma_f32_32x32x16_f16(wfA[s], bf[2][s], a2, 0, 0, 0);
                a3 = __builtin_amdgcn_mfma_f32_32x32x16_f16(wfA[s], bf[3][s], a3, 0, 0, 0);
            }
            float p0 = 0.f, p1 = 0.f, p2 = 0.f, p3 = 0.f;
            #pragma unroll
            for (int r = 0; r < 16; ++r) {
                p0 += a0[r] * a0[r]; p1 += a1[r] * a1[r];
                p2 += a2[r] * a2[r]; p3 += a3[r] * a3[r];
            }
            sP[0] = p0; sP[1] = p1; sP[2] = p2; sP[3] = p3;
        }

        // issue next comp's tile-0 loads (overlap with tile-1 MFMA below)
        if (q < 7) {
            #pragma unroll
            for (int s = 0; s < 5; ++s)
                wfA[s] = wp[((size_t)(c + 1) * 2 + 0) * 5 * WFRAG_HALF8S + s * WFRAG_HALF8S + lane];
        }

        {   // tile 1: z-rows 32..63
            floatx16 a0 = {0.f}, a1 = {0.f}, a2 = {0.f}, a3 = {0.f};
            #pragma unroll
            for (int s = 0; s < 5; ++s) {
                a0 = __builtin_amdgcn_mfma_f32_32x32x16_f16(wfB[s], bf[0][s], a0, 0, 0, 0);
                a1 = __builtin_amdgcn_mfma_f32_32x32x16_f16(wfB[s], bf[1][s], a1, 0, 0, 0);
                a2 = __builtin_amdgcn_mfma_f32_32x32x16_f16(wfB[s], bf[2][s], a2, 0, 0, 0);
                a3 = __builtin_amdgcn_mfma_f32_32x32x16_f16(wfB[s], bf[3][s], a3, 0, 0, 0);
            }
            float p0 = 0.f, p1 = 0.f, p2 = 0.f, p3 = 0.f;
            #pragma unroll
            for (int r = 0; r < 16; ++r) {
                p0 += a0[r] * a0[r]; p1 += a1[r] * a1[r];
                p2 += a2[r] * a2[r]; p3 += a3[r] * a3[r];
            }
            sP[0] += p0; sP[1] += p1; sP[2] += p2; sP[3] += p3;
        }

        const float ck = cst[c];
        #pragma unroll
        for (int g = 0; g < 4; ++g) {
            float sfull = sP[g] + __shfl_xor(sP[g], 32);
            float lp = ck - 0.5f * sfull;
            float nm = fmaxf(mx[g], lp);
            sm[g] = sm[g] * __expf(mx[g] - nm) + __expf(lp - nm);
            mx[g] = nm;
        }
    }

    // ---- merge the 4 slices in-block ----
    if (h == 0) {
        #pragma unroll
        for (int g = 0; g < 4; ++g)
            part[wave][g * 32 + col] = make_float2(mx[g], sm[g]);
    }
    __syncthreads();

    if (tid < 128) {
        float2 p0 = part[0][tid], p1 = part[1][tid];
        float2 p2 = part[2][tid], p3 = part[3][tid];
        float m = fmaxf(fmaxf(p0.x, p1.x), fmaxf(p2.x, p3.x));
        float s = p0.y * __expf(p0.x - m) + p1.y * __expf(p1.x - m)
                + p2.y * __expf(p2.x - m) + p3.y * __expf(p3.x - m);
        out[ptbase + tid] = m + logf(s);
    }
}

// ---------------------------------------------------------------------------
extern "C" void kernel_launch(void* const* d_in, const int* in_sizes, int n_in,
                              void* d_out, int out_size, void* d_ws, size_t ws_size,
                              hipStream_t stream) {
    const float* X   = (const float*)d_in[0];
    const float* loc = (const float*)d_in[1];
    const float* cov = (const float*)d_in[2];
    const float* pi  = (const float*)d_in[3];
    float* out = (float*)d_out;

    char* ws = (char*)d_ws;
    _Float16* wt = (_Float16*)ws;                              // 320 KB
    float* cstp  = (float*)(ws + (size_t)KCOMP * WCOMP_BYTES); // 128 B

    const int n = in_sizes[0] / DDIM;   // 65536

    gmm_prep<<<KCOMP, 64, 0, stream>>>(loc, cov, pi, wt, cstp);
    gmm_main<<<n / 128, 256, 0, stream>>>(X, wt, cstp, out);
}